// Round 2
// baseline (277.268 us; speedup 1.0000x reference)
//
#include <hip/hip_runtime.h>
#include <math.h>

// Problem constants: B=16, N=128, M=64, D=512, H=4, K=128, L=3

// Workspace layout (floats)
#define OFF_W   0                         // w[bn][d]            : 2048*512
#define OFF_R   (2048*512)                // r[b*64+m][d]        : 1024*512
#define OFF_RT  (OFF_R + 1024*512)        // rT[b][d][m]         : 16*512*64
#define OFF_V   (OFF_RT + 16*512*64)      // v[d][h]             : 512*4
#define OFF_G   (OFF_V + 2048)            // G[b][h][d]          : 16*4*512
#define OFF_SW  (OFF_G + 32768)           // SW[b][h]            : 16*4
#define OFF_HM  (OFF_SW + 64)             // hm[b][512]          : 16*512

// ---------------------------------------------------------------------------
// Kernel 1: fused projections + rT transpose + prep_v + zero G/SW
// blocks [0,256): w-gemm, [256,384): r-gemm (also writes rT), [384,392): prep
// ---------------------------------------------------------------------------
__global__ __launch_bounds__(256) void proj_gemm(
    const float* __restrict__ word, const float* __restrict__ rel,
    const float* __restrict__ Wn_w, const float* __restrict__ Wn_b,
    const float* __restrict__ Wr_w, const float* __restrict__ Wr_b,
    const float* __restrict__ lin_w, const float* __restrict__ score_w,
    float* __restrict__ ws)
{
    int blk = blockIdx.x;
    const int t = threadIdx.x;

    if (blk >= 384) {
        // ---- prep block: zero G/SW + compute v[h,d] = lin_w[h,d,:]·score_w[h,:]
        int gid = (blk - 384) * 256 + t;          // 0..2047
        float* Gz = ws + OFF_G + gid * 16;
        float4 z = make_float4(0.f, 0.f, 0.f, 0.f);
        *(float4*)(Gz + 0)  = z; *(float4*)(Gz + 4)  = z;
        *(float4*)(Gz + 8)  = z; *(float4*)(Gz + 12) = z;
        if (gid < 64) ws[OFF_SW + gid] = 0.f;
        int h = gid >> 9, d = gid & 511;
        const float* lw = lin_w + (size_t)(h * 512 + d) * 128;
        const float* sw = score_w + h * 128;
        float acc = 0.f;
        #pragma unroll 4
        for (int k = 0; k < 128; k += 4) {
            float4 a = *(const float4*)(lw + k);
            float4 b = *(const float4*)(sw + k);
            acc = fmaf(a.x, b.x, acc); acc = fmaf(a.y, b.y, acc);
            acc = fmaf(a.z, b.z, acc); acc = fmaf(a.w, b.w, acc);
        }
        ws[OFF_V + d * 4 + h] = acc;
        return;
    }

    const float *A, *W, *bias;
    float* C;
    int rowTile, colTile;
    bool isR = (blk >= 256);
    if (!isR) {
        A = word; W = Wn_w; bias = Wn_b; C = ws + OFF_W;
        rowTile = blk >> 3; colTile = blk & 7;
    } else {
        int b2 = blk - 256;
        A = rel; W = Wr_w; bias = Wr_b; C = ws + OFF_R;
        rowTile = b2 >> 3; colTile = b2 & 7;
    }
    const int row0 = rowTile * 64, col0 = colTile * 64;

    __shared__ float As[16][68];
    __shared__ float Bs[16][64];

    const int tx = t & 15, ty = t >> 4;
    const int lr = t >> 2, lk = (t & 3) << 2;
    const int bk = t >> 4, bc = (t & 15) << 2;

    float acc[4][4] = {};

    for (int k0 = 0; k0 < 512; k0 += 16) {
        float4 a4 = *(const float4*)(A + (size_t)(row0 + lr) * 512 + k0 + lk);
        As[lk + 0][lr] = a4.x; As[lk + 1][lr] = a4.y;
        As[lk + 2][lr] = a4.z; As[lk + 3][lr] = a4.w;
        *(float4*)&Bs[bk][bc] = *(const float4*)(W + (size_t)(k0 + bk) * 512 + col0 + bc);
        __syncthreads();
        #pragma unroll
        for (int kk = 0; kk < 16; kk++) {
            float4 av = *(float4*)&As[kk][ty << 2];
            float4 bv = *(float4*)&Bs[kk][tx << 2];
            float aa[4] = {av.x, av.y, av.z, av.w};
            float bb[4] = {bv.x, bv.y, bv.z, bv.w};
            #pragma unroll
            for (int i = 0; i < 4; i++)
                #pragma unroll
                for (int j = 0; j < 4; j++)
                    acc[i][j] = fmaf(aa[i], bb[j], acc[i][j]);
        }
        __syncthreads();
    }
    float4 bv = *(const float4*)(bias + col0 + (tx << 2));
    float bb[4] = {bv.x, bv.y, bv.z, bv.w};
    #pragma unroll
    for (int i = 0; i < 4; i++) {
        int row = row0 + (ty << 2) + i;
        float o[4];
        #pragma unroll
        for (int j = 0; j < 4; j++) o[j] = acc[i][j] + bb[j];
        *(float4*)(C + (size_t)row * 512 + col0 + (tx << 2)) =
            make_float4(o[0], o[1], o[2], o[3]);
        if (isR) {
            // rT[b][d][m], b = row>>6, m = row&63, d = col
            int bb2 = row >> 6, m = row & 63;
            float* rt = ws + OFF_RT + (size_t)bb2 * 32768 + m;
            #pragma unroll
            for (int j = 0; j < 4; j++)
                rt[(size_t)(col0 + (tx << 2) + j) * 64] = o[j];
        }
    }
}

// ---------------------------------------------------------------------------
// Kernel 2: attention. Block = (b, n-pair), 512 threads (8 waves).
// Phase1: wave=(nl,dq), lane=m — no shuffles, scores via rT.
// Phase2: wave=(nl,h), lane=m — softmax.
// Phase3: wave=(nl,dq), lanes cover d — g accumulation, LDS-reduced,
//         one atomicAdd per (block, h, d).
// ---------------------------------------------------------------------------
__global__ __launch_bounds__(512, 8) void attn_kernel(
    const float* __restrict__ mask, float* __restrict__ ws)
{
    __shared__ float s_lds[2][4][64][4];
    __shared__ float wts_lds[2][64][4];
    __shared__ float g_part[2][4][512];

    const int t = threadIdx.x;
    const int lane = t & 63;
    const int wv = __builtin_amdgcn_readfirstlane(t >> 6);
    const int b  = blockIdx.x >> 6;
    const int bn0 = blockIdx.x * 2;

    // ---- Phase 1: s[m,h] partials over d-quarter
    {
        const int nl = wv >> 2, dq = wv & 3;
        const int bn = bn0 + nl;
        const float* wrow = ws + OFF_W + (size_t)bn * 512 + dq * 128;
        const float* rT   = ws + OFF_RT + (size_t)b * 32768 + dq * 128 * 64 + lane;
        const float* vb   = ws + OFF_V + dq * 512;
        float s0 = 0.f, s1 = 0.f, s2 = 0.f, s3 = 0.f;
        #pragma unroll 2
        for (int dd = 0; dd < 128; dd += 4) {
            float r0 = rT[(dd + 0) * 64];
            float r1 = rT[(dd + 1) * 64];
            float r2 = rT[(dd + 2) * 64];
            float r3 = rT[(dd + 3) * 64];
            float w0 = wrow[dd + 0], w1 = wrow[dd + 1];
            float w2 = wrow[dd + 2], w3 = wrow[dd + 3];
            float4 v0 = *(const float4*)(vb + (dd + 0) * 4);
            float4 v1 = *(const float4*)(vb + (dd + 1) * 4);
            float4 v2 = *(const float4*)(vb + (dd + 2) * 4);
            float4 v3 = *(const float4*)(vb + (dd + 3) * 4);
            float h0 = fmaxf(w0 * r0, 0.f);
            float h1 = fmaxf(w1 * r1, 0.f);
            float h2 = fmaxf(w2 * r2, 0.f);
            float h3 = fmaxf(w3 * r3, 0.f);
            s0 = fmaf(h0, v0.x, s0); s1 = fmaf(h0, v0.y, s1);
            s2 = fmaf(h0, v0.z, s2); s3 = fmaf(h0, v0.w, s3);
            s0 = fmaf(h1, v1.x, s0); s1 = fmaf(h1, v1.y, s1);
            s2 = fmaf(h1, v1.z, s2); s3 = fmaf(h1, v1.w, s3);
            s0 = fmaf(h2, v2.x, s0); s1 = fmaf(h2, v2.y, s1);
            s2 = fmaf(h2, v2.z, s2); s3 = fmaf(h2, v2.w, s3);
            s0 = fmaf(h3, v3.x, s0); s1 = fmaf(h3, v3.y, s1);
            s2 = fmaf(h3, v3.z, s2); s3 = fmaf(h3, v3.w, s3);
        }
        *(float4*)&s_lds[nl][dq][lane][0] = make_float4(s0, s1, s2, s3);
    }
    __syncthreads();

    // ---- Phase 2: softmax per (n,h), lane=m
    {
        const int nl = wv >> 2, h = wv & 3;
        const int m = lane;
        float s = s_lds[nl][0][m][h] + s_lds[nl][1][m][h]
                + s_lds[nl][2][m][h] + s_lds[nl][3][m][h];
        float mx = s;
        #pragma unroll
        for (int off = 32; off > 0; off >>= 1)
            mx = fmaxf(mx, __shfl_xor(mx, off));
        float e = expf(s - mx);
        float sum = e;
        #pragma unroll
        for (int off = 32; off > 0; off >>= 1)
            sum += __shfl_xor(sum, off);
        float wt = e / sum * mask[b * 64 + m];
        wts_lds[nl][m][h] = wt;
        float swv = wt;
        #pragma unroll
        for (int off = 32; off > 0; off >>= 1)
            swv += __shfl_xor(swv, off);
        if (m == 0) atomicAdd(&ws[OFF_SW + b * 4 + h], swv);
    }
    __syncthreads();

    // ---- Phase 3: g[h,d] per n, accumulate into LDS partials
    {
        const int nl = wv >> 2, dq = wv & 3;
        const int bn = bn0 + nl;
        const int d0 = dq * 128 + lane * 2;
        const float* wrow = ws + OFF_W + (size_t)bn * 512;
        const float* rb   = ws + OFF_R + (size_t)b * 32768 + d0;
        float2 wd = *(const float2*)(wrow + d0);
        float g00 = 0.f, g01 = 0.f, g10 = 0.f, g11 = 0.f;
        float g20 = 0.f, g21 = 0.f, g30 = 0.f, g31 = 0.f;
        #pragma unroll 4
        for (int m = 0; m < 64; m++) {
            float2 rv = *(const float2*)(rb + (size_t)m * 512);
            float4 wt = *(const float4*)&wts_lds[nl][m][0];
            float h0 = fmaxf(wd.x * rv.x, 0.f);
            float h1 = fmaxf(wd.y * rv.y, 0.f);
            g00 = fmaf(wt.x, h0, g00); g01 = fmaf(wt.x, h1, g01);
            g10 = fmaf(wt.y, h0, g10); g11 = fmaf(wt.y, h1, g11);
            g20 = fmaf(wt.z, h0, g20); g21 = fmaf(wt.z, h1, g21);
            g30 = fmaf(wt.w, h0, g30); g31 = fmaf(wt.w, h1, g31);
        }
        *(float2*)&g_part[nl][0][d0] = make_float2(g00, g01);
        *(float2*)&g_part[nl][1][d0] = make_float2(g10, g11);
        *(float2*)&g_part[nl][2][d0] = make_float2(g20, g21);
        *(float2*)&g_part[nl][3][d0] = make_float2(g30, g31);
    }
    __syncthreads();

    // ---- Reduce over nl and atomically add to G[b]
    {
        float* G = ws + OFF_G + (size_t)b * 2048;
        #pragma unroll
        for (int c = t; c < 2048; c += 512) {
            int h = c >> 9, d = c & 511;
            atomicAdd(&G[c], g_part[0][h][d] + g_part[1][h][d]);
        }
    }
}

// ---------------------------------------------------------------------------
// Kernel 3: hm[b][h*128+k] = (G[b,h,:]·lin_w[h,:,k] + lin_b[h,k]*SW[b,h])/128
// grid = 64 blocks (b,h), 256 threads (k x 2 d-halves)
// ---------------------------------------------------------------------------
__global__ __launch_bounds__(256) void head1_kernel(
    const float* __restrict__ lin_w, const float* __restrict__ lin_b,
    float* __restrict__ ws)
{
    const int b = blockIdx.x >> 2, h = blockIdx.x & 3;
    const int t = threadIdx.x;
    const int half = __builtin_amdgcn_readfirstlane(t >> 7);
    const int k = t & 127;
    __shared__ float red[128];

    const float* Gp = ws + OFF_G + (size_t)b * 2048 + h * 512 + half * 256;
    const float* lw = lin_w + ((size_t)(h * 512 + half * 256)) * 128 + k;
    float acc = 0.f;
    #pragma unroll 4
    for (int d = 0; d < 256; d++)
        acc = fmaf(Gp[d], lw[(size_t)d * 128], acc);
    if (half) red[k] = acc;
    __syncthreads();
    if (!half) {
        float sw = ws[OFF_SW + b * 4 + h];
        float tot = acc + red[k] + lin_b[h * 128 + k] * sw;
        ws[OFF_HM + (size_t)b * 512 + h * 128 + k] = tot * (1.0f / 128.0f);
    }
}

// ---------------------------------------------------------------------------
// Kernel 4: out = relu(hm @ final_w + final_b); logits = out @ fc_w + fc_b
// grid = 16 blocks (b), 512 threads
// ---------------------------------------------------------------------------
__global__ __launch_bounds__(512) void head2_kernel(
    const float* __restrict__ final_w, const float* __restrict__ final_b,
    const float* __restrict__ fc_w, const float* __restrict__ fc_b,
    const float* __restrict__ ws, float* __restrict__ out)
{
    const int b = blockIdx.x;
    const int t = threadIdx.x;
    __shared__ float hm[512];
    __shared__ float os[512];

    hm[t] = ws[OFF_HM + (size_t)b * 512 + t];
    __syncthreads();

    float acc = final_b[t];
    #pragma unroll 4
    for (int d = 0; d < 512; d++)
        acc = fmaf(hm[d], final_w[(size_t)d * 512 + t], acc);
    os[t] = fmaxf(acc, 0.f);
    __syncthreads();

    if (t < 192) {
        int l = t >> 6, ln = t & 63;
        float a = 0.f;
        for (int i = ln; i < 512; i += 64)
            a = fmaf(os[i], fc_w[i * 3 + l], a);
        #pragma unroll
        for (int off = 32; off > 0; off >>= 1)
            a += __shfl_xor(a, off);
        if (ln == 0) out[b * 3 + l] = a + fc_b[l];
    }
}

// ---------------------------------------------------------------------------
extern "C" void kernel_launch(void* const* d_in, const int* in_sizes, int n_in,
                              void* d_out, int out_size, void* d_ws, size_t ws_size,
                              hipStream_t stream)
{
    const float* word    = (const float*)d_in[0];
    const float* rel     = (const float*)d_in[1];
    const float* mask    = (const float*)d_in[2];
    const float* Wn_w    = (const float*)d_in[3];
    const float* Wn_b    = (const float*)d_in[4];
    const float* Wr_w    = (const float*)d_in[5];
    const float* Wr_b    = (const float*)d_in[6];
    const float* lin_w   = (const float*)d_in[7];
    const float* lin_b   = (const float*)d_in[8];
    const float* score_w = (const float*)d_in[9];
    // d_in[10] score_b cancels in softmax — unused
    const float* final_w = (const float*)d_in[11];
    const float* final_b = (const float*)d_in[12];
    const float* fc_w    = (const float*)d_in[13];
    const float* fc_b    = (const float*)d_in[14];
    float* ws  = (float*)d_ws;
    float* out = (float*)d_out;

    proj_gemm<<<392, 256, 0, stream>>>(word, rel, Wn_w, Wn_b, Wr_w, Wr_b,
                                       lin_w, score_w, ws);
    attn_kernel<<<1024, 512, 0, stream>>>(mask, ws);
    head1_kernel<<<64, 256, 0, stream>>>(lin_w, lin_b, ws);
    head2_kernel<<<16, 512, 0, stream>>>(final_w, final_b, fc_w, fc_b, ws, out);
}

// Round 3
// 276.369 us; speedup vs baseline: 1.0033x; 1.0033x over previous
//
#include <hip/hip_runtime.h>
#include <math.h>

// Problem constants: B=16, N=128, M=64, D=512, H=4, K=128, L=3

// Workspace layout (floats)
#define OFF_W   0                         // w[bn][d]            : 2048*512
#define OFF_R   (2048*512)                // r[b*64+m][d]        : 1024*512
#define OFF_V   (OFF_R + 1024*512)        // v[d][h]             : 512*4
#define OFF_G   (OFF_V + 2048)            // G[b][h][d]          : 16*4*512
#define OFF_SW  (OFF_G + 32768)           // SW[b][h]            : 16*4

// ---------------------------------------------------------------------------
// Kernel 1: fused projections + prep_v + zero G/SW
// blocks [0,256): w-gemm, [256,384): r-gemm, [384,392): prep
// 64x64 tile, 256 threads, 4x4 microtile, BK=16, register-prefetch pipeline.
// ---------------------------------------------------------------------------
__global__ __launch_bounds__(256) void proj_gemm(
    const float* __restrict__ word, const float* __restrict__ rel,
    const float* __restrict__ Wn_w, const float* __restrict__ Wn_b,
    const float* __restrict__ Wr_w, const float* __restrict__ Wr_b,
    const float* __restrict__ lin_w, const float* __restrict__ score_w,
    float* __restrict__ ws)
{
    int blk = blockIdx.x;
    const int t = threadIdx.x;

    if (blk >= 384) {
        // prep: zero G/SW + v[d][h] = lin_w[h,d,:]·score_w[h,:]
        int gid = (blk - 384) * 256 + t;          // 0..2047
        float* Gz = ws + OFF_G + gid * 16;
        float4 z = make_float4(0.f, 0.f, 0.f, 0.f);
        *(float4*)(Gz + 0)  = z; *(float4*)(Gz + 4)  = z;
        *(float4*)(Gz + 8)  = z; *(float4*)(Gz + 12) = z;
        if (gid < 64) ws[OFF_SW + gid] = 0.f;
        int h = gid >> 9, d = gid & 511;
        const float* lw = lin_w + (size_t)(h * 512 + d) * 128;
        const float* sw = score_w + h * 128;
        float acc = 0.f;
        #pragma unroll 8
        for (int k = 0; k < 128; k += 4) {
            float4 a = *(const float4*)(lw + k);
            float4 bq = *(const float4*)(sw + k);
            acc = fmaf(a.x, bq.x, acc); acc = fmaf(a.y, bq.y, acc);
            acc = fmaf(a.z, bq.z, acc); acc = fmaf(a.w, bq.w, acc);
        }
        ws[OFF_V + d * 4 + h] = acc;
        return;
    }

    const float *A, *W, *bias;
    float* C;
    int rowTile, colTile;
    if (blk < 256) {
        A = word; W = Wn_w; bias = Wn_b; C = ws + OFF_W;
        rowTile = blk >> 3; colTile = blk & 7;
    } else {
        int b2 = blk - 256;
        A = rel; W = Wr_w; bias = Wr_b; C = ws + OFF_R;
        rowTile = b2 >> 3; colTile = b2 & 7;
    }
    const int row0 = rowTile * 64, col0 = colTile * 64;

    __shared__ float As[16][68];
    __shared__ float Bs[16][64];

    const int tx = t & 15, ty = t >> 4;
    const int lr = t >> 2, lk = (t & 3) << 2;
    const int bk = t >> 4, bc = (t & 15) << 2;

    float acc[4][4] = {};

    const float* Aptr = A + (size_t)(row0 + lr) * 512 + lk;
    const float* Wptr = W + (size_t)bk * 512 + col0 + bc;
    float4 pa = *(const float4*)Aptr;
    float4 pb = *(const float4*)Wptr;

    for (int k0 = 0; k0 < 512; k0 += 16) {
        As[lk + 0][lr] = pa.x; As[lk + 1][lr] = pa.y;
        As[lk + 2][lr] = pa.z; As[lk + 3][lr] = pa.w;
        *(float4*)&Bs[bk][bc] = pb;
        __syncthreads();
        if (k0 + 16 < 512) {
            pa = *(const float4*)(Aptr + k0 + 16);
            pb = *(const float4*)(Wptr + (size_t)(k0 + 16) * 512);
        }
        #pragma unroll
        for (int kk = 0; kk < 16; kk++) {
            float4 av = *(float4*)&As[kk][ty << 2];
            float4 bv = *(float4*)&Bs[kk][tx << 2];
            float aa[4] = {av.x, av.y, av.z, av.w};
            float bb[4] = {bv.x, bv.y, bv.z, bv.w};
            #pragma unroll
            for (int i = 0; i < 4; i++)
                #pragma unroll
                for (int j = 0; j < 4; j++)
                    acc[i][j] = fmaf(aa[i], bb[j], acc[i][j]);
        }
        __syncthreads();
    }
    float4 bv = *(const float4*)(bias + col0 + (tx << 2));
    float bb[4] = {bv.x, bv.y, bv.z, bv.w};
    #pragma unroll
    for (int i = 0; i < 4; i++) {
        float4 o;
        o.x = acc[i][0] + bb[0]; o.y = acc[i][1] + bb[1];
        o.z = acc[i][2] + bb[2]; o.w = acc[i][3] + bb[3];
        *(float4*)(C + (size_t)(row0 + (ty << 2) + i) * 512 + col0 + (tx << 2)) = o;
    }
}

// ---------------------------------------------------------------------------
// Kernel 2: attention. Block = (b, 2n), 512 threads (8 waves).
// r staged through LDS in 16-m chunks (32 KB), read once per block per phase.
// Phase1: wave=(nl,mg) — per m: b128 LDS reads, butterfly reduce over d.
// Phase2: wave=(nl,h), lane=m — softmax.
// Phase3: wave=(nl,dq), lane=2d — g accumulation from same LDS chunks.
// ---------------------------------------------------------------------------
__global__ __launch_bounds__(512) void attn_kernel(
    const float* __restrict__ mask, float* __restrict__ ws)
{
    __shared__ float r_lds[16 * 512];       // 32 KB chunk
    __shared__ float s_lds[2][64][4];
    __shared__ float wts_lds[2][64][4];

    const int t = threadIdx.x;
    const int lane = t & 63;
    const int wv = __builtin_amdgcn_readfirstlane(t >> 6);
    const int b  = blockIdx.x >> 6;
    const int np = blockIdx.x & 63;

    const float* rbase = ws + OFF_R + (size_t)b * 32768;
    const int nl = wv >> 2;
    const int bn = b * 128 + np * 2 + nl;
    const float* wrow = ws + OFF_W + (size_t)bn * 512;

    // ---- Phase 1 registers: lane covers d in {4L..4L+3} and {256+4L..+3}
    const int mg = wv & 3;
    const float* vbase = ws + OFF_V;
    float4 wA = *(const float4*)(wrow + 4 * lane);
    float4 wB = *(const float4*)(wrow + 256 + 4 * lane);
    float4 vA0 = *(const float4*)(vbase + (4 * lane + 0) * 4);
    float4 vA1 = *(const float4*)(vbase + (4 * lane + 1) * 4);
    float4 vA2 = *(const float4*)(vbase + (4 * lane + 2) * 4);
    float4 vA3 = *(const float4*)(vbase + (4 * lane + 3) * 4);
    float4 vB0 = *(const float4*)(vbase + (256 + 4 * lane + 0) * 4);
    float4 vB1 = *(const float4*)(vbase + (256 + 4 * lane + 1) * 4);
    float4 vB2 = *(const float4*)(vbase + (256 + 4 * lane + 2) * 4);
    float4 vB3 = *(const float4*)(vbase + (256 + 4 * lane + 3) * 4);

    for (int c = 0; c < 4; c++) {
        const float* rg = rbase + c * 8192;
        #pragma unroll
        for (int q = 0; q < 4; q++) {
            int idx = (t + q * 512) * 4;
            *(float4*)&r_lds[idx] = *(const float4*)&rg[idx];
        }
        __syncthreads();
        #pragma unroll
        for (int i = 0; i < 4; i++) {
            const int ml = mg * 4 + i;
            const float* rr = &r_lds[ml * 512];
            float4 rA = *(const float4*)(rr + 4 * lane);
            float4 rB = *(const float4*)(rr + 256 + 4 * lane);
            float a0 = 0.f, a1 = 0.f, a2 = 0.f, a3 = 0.f;
            float h;
            h = fmaxf(wA.x * rA.x, 0.f);
            a0 = fmaf(h, vA0.x, a0); a1 = fmaf(h, vA0.y, a1);
            a2 = fmaf(h, vA0.z, a2); a3 = fmaf(h, vA0.w, a3);
            h = fmaxf(wA.y * rA.y, 0.f);
            a0 = fmaf(h, vA1.x, a0); a1 = fmaf(h, vA1.y, a1);
            a2 = fmaf(h, vA1.z, a2); a3 = fmaf(h, vA1.w, a3);
            h = fmaxf(wA.z * rA.z, 0.f);
            a0 = fmaf(h, vA2.x, a0); a1 = fmaf(h, vA2.y, a1);
            a2 = fmaf(h, vA2.z, a2); a3 = fmaf(h, vA2.w, a3);
            h = fmaxf(wA.w * rA.w, 0.f);
            a0 = fmaf(h, vA3.x, a0); a1 = fmaf(h, vA3.y, a1);
            a2 = fmaf(h, vA3.z, a2); a3 = fmaf(h, vA3.w, a3);
            h = fmaxf(wB.x * rB.x, 0.f);
            a0 = fmaf(h, vB0.x, a0); a1 = fmaf(h, vB0.y, a1);
            a2 = fmaf(h, vB0.z, a2); a3 = fmaf(h, vB0.w, a3);
            h = fmaxf(wB.y * rB.y, 0.f);
            a0 = fmaf(h, vB1.x, a0); a1 = fmaf(h, vB1.y, a1);
            a2 = fmaf(h, vB1.z, a2); a3 = fmaf(h, vB1.w, a3);
            h = fmaxf(wB.z * rB.z, 0.f);
            a0 = fmaf(h, vB2.x, a0); a1 = fmaf(h, vB2.y, a1);
            a2 = fmaf(h, vB2.z, a2); a3 = fmaf(h, vB2.w, a3);
            h = fmaxf(wB.w * rB.w, 0.f);
            a0 = fmaf(h, vB3.x, a0); a1 = fmaf(h, vB3.y, a1);
            a2 = fmaf(h, vB3.z, a2); a3 = fmaf(h, vB3.w, a3);
            #pragma unroll
            for (int off = 32; off > 0; off >>= 1) {
                a0 += __shfl_xor(a0, off);
                a1 += __shfl_xor(a1, off);
                a2 += __shfl_xor(a2, off);
                a3 += __shfl_xor(a3, off);
            }
            if (lane == 0) {
                const int m = c * 16 + ml;
                s_lds[nl][m][0] = a0; s_lds[nl][m][1] = a1;
                s_lds[nl][m][2] = a2; s_lds[nl][m][3] = a3;
            }
        }
        __syncthreads();
    }

    // ---- Phase 2: softmax per (n,h), lane=m
    {
        const int h = wv & 3, m = lane;
        float s = s_lds[nl][m][h];
        float mx = s;
        #pragma unroll
        for (int off = 32; off > 0; off >>= 1)
            mx = fmaxf(mx, __shfl_xor(mx, off));
        float e = expf(s - mx);
        float sum = e;
        #pragma unroll
        for (int off = 32; off > 0; off >>= 1)
            sum += __shfl_xor(sum, off);
        float wt = e / sum * mask[b * 64 + m];
        wts_lds[nl][m][h] = wt;
        float swv = wt;
        #pragma unroll
        for (int off = 32; off > 0; off >>= 1)
            swv += __shfl_xor(swv, off);
        if (lane == 0) atomicAdd(&ws[OFF_SW + b * 4 + h], swv);
    }
    __syncthreads();

    // ---- Phase 3: g[h,d] per n from the same LDS chunks
    {
        const int dq = wv & 3;
        const int d0 = dq * 128 + lane * 2;
        float2 w2 = *(const float2*)(wrow + d0);
        float g00 = 0.f, g01 = 0.f, g10 = 0.f, g11 = 0.f;
        float g20 = 0.f, g21 = 0.f, g30 = 0.f, g31 = 0.f;
        for (int c = 0; c < 4; c++) {
            const float* rg = rbase + c * 8192;
            #pragma unroll
            for (int q = 0; q < 4; q++) {
                int idx = (t + q * 512) * 4;
                *(float4*)&r_lds[idx] = *(const float4*)&rg[idx];
            }
            __syncthreads();
            #pragma unroll 4
            for (int ml = 0; ml < 16; ml++) {
                const int m = c * 16 + ml;
                float2 rv = *(const float2*)&r_lds[ml * 512 + d0];
                float4 wt = *(const float4*)&wts_lds[nl][m][0];
                float h0 = fmaxf(w2.x * rv.x, 0.f);
                float h1 = fmaxf(w2.y * rv.y, 0.f);
                g00 = fmaf(wt.x, h0, g00); g01 = fmaf(wt.x, h1, g01);
                g10 = fmaf(wt.y, h0, g10); g11 = fmaf(wt.y, h1, g11);
                g20 = fmaf(wt.z, h0, g20); g21 = fmaf(wt.z, h1, g21);
                g30 = fmaf(wt.w, h0, g30); g31 = fmaf(wt.w, h1, g31);
            }
            __syncthreads();
        }
        float* G = ws + OFF_G + (size_t)b * 2048 + d0;
        atomicAdd(&G[0 * 512],     g00); atomicAdd(&G[0 * 512 + 1], g01);
        atomicAdd(&G[1 * 512],     g10); atomicAdd(&G[1 * 512 + 1], g11);
        atomicAdd(&G[2 * 512],     g20); atomicAdd(&G[2 * 512 + 1], g21);
        atomicAdd(&G[3 * 512],     g30); atomicAdd(&G[3 * 512 + 1], g31);
    }
}

// ---------------------------------------------------------------------------
// Kernel 3: fused epilogue per batch. 16 blocks x 512 threads.
// hm = (G·lin_w + lin_b·SW)/128 ; out = relu(hm@final_w+final_b);
// logits = out @ fc_w + fc_b
// ---------------------------------------------------------------------------
__global__ __launch_bounds__(512) void head_kernel(
    const float* __restrict__ lin_w, const float* __restrict__ lin_b,
    const float* __restrict__ final_w, const float* __restrict__ final_b,
    const float* __restrict__ fc_w, const float* __restrict__ fc_b,
    const float* __restrict__ ws, float* __restrict__ out)
{
    const int b = blockIdx.x;
    const int t = threadIdx.x;
    __shared__ float Gs[2048];
    __shared__ float hm[512];
    __shared__ float os[512];
    __shared__ float SWs[4];

    const float* G = ws + OFF_G + (size_t)b * 2048;
    *(float4*)&Gs[t * 4] = *(const float4*)&G[t * 4];
    if (t < 4) SWs[t] = ws[OFF_SW + b * 4 + t];
    __syncthreads();

    // hm: one (h,k) per thread
    {
        const int h = t >> 7, k = t & 127;
        float acc = lin_b[h * 128 + k] * SWs[h];
        const float* lwp = lin_w + ((size_t)h * 512) * 128 + k;
        const float* gp = Gs + h * 512;
        #pragma unroll 8
        for (int d = 0; d < 512; d++)
            acc = fmaf(gp[d], lwp[(size_t)d * 128], acc);
        hm[t] = acc * (1.0f / 128.0f);
    }
    __syncthreads();

    // out = relu(hm @ final_w + final_b): one j per thread
    {
        float acc = final_b[t];
        #pragma unroll 8
        for (int d = 0; d < 512; d++)
            acc = fmaf(hm[d], final_w[(size_t)d * 512 + t], acc);
        os[t] = fmaxf(acc, 0.f);
    }
    __syncthreads();

    if (t < 192) {
        int l = t >> 6, ln = t & 63;
        float a = 0.f;
        #pragma unroll 4
        for (int i = ln; i < 512; i += 64)
            a = fmaf(os[i], fc_w[i * 3 + l], a);
        #pragma unroll
        for (int off = 32; off > 0; off >>= 1)
            a += __shfl_xor(a, off);
        if (ln == 0) out[b * 3 + l] = a + fc_b[l];
    }
}

// ---------------------------------------------------------------------------
extern "C" void kernel_launch(void* const* d_in, const int* in_sizes, int n_in,
                              void* d_out, int out_size, void* d_ws, size_t ws_size,
                              hipStream_t stream)
{
    const float* word    = (const float*)d_in[0];
    const float* rel     = (const float*)d_in[1];
    const float* mask    = (const float*)d_in[2];
    const float* Wn_w    = (const float*)d_in[3];
    const float* Wn_b    = (const float*)d_in[4];
    const float* Wr_w    = (const float*)d_in[5];
    const float* Wr_b    = (const float*)d_in[6];
    const float* lin_w   = (const float*)d_in[7];
    const float* lin_b   = (const float*)d_in[8];
    const float* score_w = (const float*)d_in[9];
    // d_in[10] score_b cancels in softmax — unused
    const float* final_w = (const float*)d_in[11];
    const float* final_b = (const float*)d_in[12];
    const float* fc_w    = (const float*)d_in[13];
    const float* fc_b    = (const float*)d_in[14];
    float* ws  = (float*)d_ws;
    float* out = (float*)d_out;

    proj_gemm<<<392, 256, 0, stream>>>(word, rel, Wn_w, Wn_b, Wr_w, Wr_b,
                                       lin_w, score_w, ws);
    attn_kernel<<<1024, 512, 0, stream>>>(mask, ws);
    head_kernel<<<16, 512, 0, stream>>>(lin_w, lin_b, final_w, final_b,
                                        fc_w, fc_b, ws, out);
}

// Round 4
// 244.428 us; speedup vs baseline: 1.1344x; 1.1307x over previous
//
#include <hip/hip_runtime.h>
#include <math.h>

// Problem constants: B=16, N=128, M=64, D=512, H=4, K=128, L=3

// Workspace layout (floats)
#define OFF_W   0                         // w[bn][d]            : 2048*512
#define OFF_R   (2048*512)                // r[b*64+m][d]        : 1024*512
#define OFF_V   (OFF_R + 1024*512)        // v[d][h]             : 512*4
#define OFF_G   (OFF_V + 2048)            // G[b][h][d]          : 16*4*512
#define OFF_SW  (OFF_G + 32768)           // SW[b][h]            : 16*4

// ---------------------------------------------------------------------------
// Kernel 1: fused projections + prep_v + zero G/SW   (unchanged from r3)
// blocks [0,256): w-gemm, [256,384): r-gemm, [384,392): prep
// ---------------------------------------------------------------------------
__global__ __launch_bounds__(256) void proj_gemm(
    const float* __restrict__ word, const float* __restrict__ rel,
    const float* __restrict__ Wn_w, const float* __restrict__ Wn_b,
    const float* __restrict__ Wr_w, const float* __restrict__ Wr_b,
    const float* __restrict__ lin_w, const float* __restrict__ score_w,
    float* __restrict__ ws)
{
    int blk = blockIdx.x;
    const int t = threadIdx.x;

    if (blk >= 384) {
        int gid = (blk - 384) * 256 + t;          // 0..2047
        float* Gz = ws + OFF_G + gid * 16;
        float4 z = make_float4(0.f, 0.f, 0.f, 0.f);
        *(float4*)(Gz + 0)  = z; *(float4*)(Gz + 4)  = z;
        *(float4*)(Gz + 8)  = z; *(float4*)(Gz + 12) = z;
        if (gid < 64) ws[OFF_SW + gid] = 0.f;
        int h = gid >> 9, d = gid & 511;
        const float* lw = lin_w + (size_t)(h * 512 + d) * 128;
        const float* sw = score_w + h * 128;
        float acc = 0.f;
        #pragma unroll 8
        for (int k = 0; k < 128; k += 4) {
            float4 a = *(const float4*)(lw + k);
            float4 bq = *(const float4*)(sw + k);
            acc = fmaf(a.x, bq.x, acc); acc = fmaf(a.y, bq.y, acc);
            acc = fmaf(a.z, bq.z, acc); acc = fmaf(a.w, bq.w, acc);
        }
        ws[OFF_V + d * 4 + h] = acc;
        return;
    }

    const float *A, *W, *bias;
    float* C;
    int rowTile, colTile;
    if (blk < 256) {
        A = word; W = Wn_w; bias = Wn_b; C = ws + OFF_W;
        rowTile = blk >> 3; colTile = blk & 7;
    } else {
        int b2 = blk - 256;
        A = rel; W = Wr_w; bias = Wr_b; C = ws + OFF_R;
        rowTile = b2 >> 3; colTile = b2 & 7;
    }
    const int row0 = rowTile * 64, col0 = colTile * 64;

    __shared__ float As[16][68];
    __shared__ float Bs[16][64];

    const int tx = t & 15, ty = t >> 4;
    const int lr = t >> 2, lk = (t & 3) << 2;
    const int bk = t >> 4, bc = (t & 15) << 2;

    float acc[4][4] = {};

    const float* Aptr = A + (size_t)(row0 + lr) * 512 + lk;
    const float* Wptr = W + (size_t)bk * 512 + col0 + bc;
    float4 pa = *(const float4*)Aptr;
    float4 pb = *(const float4*)Wptr;

    for (int k0 = 0; k0 < 512; k0 += 16) {
        As[lk + 0][lr] = pa.x; As[lk + 1][lr] = pa.y;
        As[lk + 2][lr] = pa.z; As[lk + 3][lr] = pa.w;
        *(float4*)&Bs[bk][bc] = pb;
        __syncthreads();
        if (k0 + 16 < 512) {
            pa = *(const float4*)(Aptr + k0 + 16);
            pb = *(const float4*)(Wptr + (size_t)(k0 + 16) * 512);
        }
        #pragma unroll
        for (int kk = 0; kk < 16; kk++) {
            float4 av = *(float4*)&As[kk][ty << 2];
            float4 bv = *(float4*)&Bs[kk][tx << 2];
            float aa[4] = {av.x, av.y, av.z, av.w};
            float bb[4] = {bv.x, bv.y, bv.z, bv.w};
            #pragma unroll
            for (int i = 0; i < 4; i++)
                #pragma unroll
                for (int j = 0; j < 4; j++)
                    acc[i][j] = fmaf(aa[i], bb[j], acc[i][j]);
        }
        __syncthreads();
    }
    float4 bv = *(const float4*)(bias + col0 + (tx << 2));
    float bb[4] = {bv.x, bv.y, bv.z, bv.w};
    #pragma unroll
    for (int i = 0; i < 4; i++) {
        float4 o;
        o.x = acc[i][0] + bb[0]; o.y = acc[i][1] + bb[1];
        o.z = acc[i][2] + bb[2]; o.w = acc[i][3] + bb[3];
        *(float4*)(C + (size_t)(row0 + (ty << 2) + i) * 512 + col0 + (tx << 2)) = o;
    }
}

// ---------------------------------------------------------------------------
// Kernel 2: attention v4. Block = (b, n-quad), 256 threads (4 waves, wave=n).
// Phase1: lane=m, r chunk-staged in LDS with +1 pad (bank-conflict-free
//         transposed reads), w/v wave-uniform scalar loads — NO shuffles.
// Softmax: in-register per wave.
// Phase3: lane=d-octet, r streamed coalesced from L2, wt LDS broadcast.
// Cross-wave LDS reduce (aliased over r-chunk) -> 2048 atomics per block.
// ---------------------------------------------------------------------------
__global__ __launch_bounds__(256) void attn_kernel(
    const float* __restrict__ mask, float* __restrict__ ws)
{
    __shared__ float smem[8256];          // r_chunk [64][129] | g_part [4][2048]
    __shared__ float wts[4][64][4];

    const int t = threadIdx.x;
    const int lane = t & 63;
    const int wv = __builtin_amdgcn_readfirstlane(t >> 6);
    const int b  = blockIdx.x >> 5;
    const int np = blockIdx.x & 31;
    const int bn = b * 128 + np * 4 + wv;

    const float* wrow  = ws + OFF_W + (size_t)bn * 512;
    const float* rb    = ws + OFF_R + (size_t)b * 32768;
    const float* vbase = ws + OFF_V;

    // ---- Phase 1: s[m=lane][h] over 4 chunks of 128 d
    float s0 = 0.f, s1 = 0.f, s2 = 0.f, s3 = 0.f;
    for (int c = 0; c < 4; c++) {
        const int d0 = c * 128;
        #pragma unroll
        for (int q = 0; q < 8; q++) {
            int fidx = q * 256 + t;               // float4 index 0..2047
            int m = fidx >> 5, dl4 = (fidx & 31) << 2;
            float4 rv = *(const float4*)&rb[(size_t)m * 512 + d0 + dl4];
            float* dst = &smem[m * 129 + dl4];
            dst[0] = rv.x; dst[1] = rv.y; dst[2] = rv.z; dst[3] = rv.w;
        }
        __syncthreads();
        const float* rr = &smem[lane * 129];
        const float* wp = wrow + d0;
        const float* vp = vbase + d0 * 4;
        #pragma unroll 8
        for (int dl = 0; dl < 128; dl++) {
            float rv  = rr[dl];
            float wvv = wp[dl];
            float4 vv = *(const float4*)&vp[dl * 4];
            float h = fmaxf(wvv * rv, 0.f);
            s0 = fmaf(h, vv.x, s0); s1 = fmaf(h, vv.y, s1);
            s2 = fmaf(h, vv.z, s2); s3 = fmaf(h, vv.w, s3);
        }
        __syncthreads();
    }

    // ---- Phase 2: softmax in-register (lane=m), write wts, SW atomics
    {
        float sv[4] = {s0, s1, s2, s3};
        float wt[4];
        float mk = mask[b * 64 + lane];
        #pragma unroll
        for (int h = 0; h < 4; h++) {
            float mx = sv[h];
            #pragma unroll
            for (int off = 32; off > 0; off >>= 1)
                mx = fmaxf(mx, __shfl_xor(mx, off));
            float e = expf(sv[h] - mx);
            float sum = e;
            #pragma unroll
            for (int off = 32; off > 0; off >>= 1)
                sum += __shfl_xor(sum, off);
            float wtt = e / sum * mk;
            wt[h] = wtt;
            float sv2 = wtt;
            #pragma unroll
            for (int off = 32; off > 0; off >>= 1)
                sv2 += __shfl_xor(sv2, off);
            if (lane == 0) atomicAdd(&ws[OFF_SW + b * 4 + h], sv2);
        }
        *(float4*)&wts[wv][lane][0] = make_float4(wt[0], wt[1], wt[2], wt[3]);
    }
    __syncthreads();

    // ---- Phase 3: g[h][d] for d = lane*8..+7, streaming r from L2
    {
        const int d0l = lane * 8;
        float wreg[8];
        *(float4*)&wreg[0] = *(const float4*)&wrow[d0l];
        *(float4*)&wreg[4] = *(const float4*)&wrow[d0l + 4];
        float g[4][8] = {};
        #pragma unroll 2
        for (int m = 0; m < 64; m++) {
            float rv[8];
            *(float4*)&rv[0] = *(const float4*)&rb[(size_t)m * 512 + d0l];
            *(float4*)&rv[4] = *(const float4*)&rb[(size_t)m * 512 + d0l + 4];
            float4 w4 = *(const float4*)&wts[wv][m][0];
            #pragma unroll
            for (int j = 0; j < 8; j++) {
                float h = fmaxf(wreg[j] * rv[j], 0.f);
                g[0][j] = fmaf(w4.x, h, g[0][j]);
                g[1][j] = fmaf(w4.y, h, g[1][j]);
                g[2][j] = fmaf(w4.z, h, g[2][j]);
                g[3][j] = fmaf(w4.w, h, g[3][j]);
            }
        }
        float* gp = &smem[wv * 2048];
        #pragma unroll
        for (int h = 0; h < 4; h++) {
            *(float4*)&gp[h * 512 + d0l]     = *(float4*)&g[h][0];
            *(float4*)&gp[h * 512 + d0l + 4] = *(float4*)&g[h][4];
        }
    }
    __syncthreads();

    // ---- Cross-wave reduce + atomics into G[b] (stride-256: 2-way banks)
    {
        float* G = ws + OFF_G + (size_t)b * 2048;
        #pragma unroll
        for (int i = 0; i < 8; i++) {
            int cidx = i * 256 + t;
            float v = smem[cidx] + smem[2048 + cidx]
                    + smem[4096 + cidx] + smem[6144 + cidx];
            atomicAdd(&G[cidx], v);
        }
    }
}

// ---------------------------------------------------------------------------
// Kernel 3: fused epilogue per batch (unchanged from r3). 16 blocks x 512.
// ---------------------------------------------------------------------------
__global__ __launch_bounds__(512) void head_kernel(
    const float* __restrict__ lin_w, const float* __restrict__ lin_b,
    const float* __restrict__ final_w, const float* __restrict__ final_b,
    const float* __restrict__ fc_w, const float* __restrict__ fc_b,
    const float* __restrict__ ws, float* __restrict__ out)
{
    const int b = blockIdx.x;
    const int t = threadIdx.x;
    __shared__ float Gs[2048];
    __shared__ float hm[512];
    __shared__ float os[512];
    __shared__ float SWs[4];

    const float* G = ws + OFF_G + (size_t)b * 2048;
    *(float4*)&Gs[t * 4] = *(const float4*)&G[t * 4];
    if (t < 4) SWs[t] = ws[OFF_SW + b * 4 + t];
    __syncthreads();

    {
        const int h = t >> 7, k = t & 127;
        float acc = lin_b[h * 128 + k] * SWs[h];
        const float* lwp = lin_w + ((size_t)h * 512) * 128 + k;
        const float* gp = Gs + h * 512;
        #pragma unroll 8
        for (int d = 0; d < 512; d++)
            acc = fmaf(gp[d], lwp[(size_t)d * 128], acc);
        hm[t] = acc * (1.0f / 128.0f);
    }
    __syncthreads();

    {
        float acc = final_b[t];
        #pragma unroll 8
        for (int d = 0; d < 512; d++)
            acc = fmaf(hm[d], final_w[(size_t)d * 512 + t], acc);
        os[t] = fmaxf(acc, 0.f);
    }
    __syncthreads();

    if (t < 192) {
        int l = t >> 6, ln = t & 63;
        float a = 0.f;
        #pragma unroll 4
        for (int i = ln; i < 512; i += 64)
            a = fmaf(os[i], fc_w[i * 3 + l], a);
        #pragma unroll
        for (int off = 32; off > 0; off >>= 1)
            a += __shfl_xor(a, off);
        if (ln == 0) out[b * 3 + l] = a + fc_b[l];
    }
}

// ---------------------------------------------------------------------------
extern "C" void kernel_launch(void* const* d_in, const int* in_sizes, int n_in,
                              void* d_out, int out_size, void* d_ws, size_t ws_size,
                              hipStream_t stream)
{
    const float* word    = (const float*)d_in[0];
    const float* rel     = (const float*)d_in[1];
    const float* mask    = (const float*)d_in[2];
    const float* Wn_w    = (const float*)d_in[3];
    const float* Wn_b    = (const float*)d_in[4];
    const float* Wr_w    = (const float*)d_in[5];
    const float* Wr_b    = (const float*)d_in[6];
    const float* lin_w   = (const float*)d_in[7];
    const float* lin_b   = (const float*)d_in[8];
    const float* score_w = (const float*)d_in[9];
    // d_in[10] score_b cancels in softmax — unused
    const float* final_w = (const float*)d_in[11];
    const float* final_b = (const float*)d_in[12];
    const float* fc_w    = (const float*)d_in[13];
    const float* fc_b    = (const float*)d_in[14];
    float* ws  = (float*)d_ws;
    float* out = (float*)d_out;

    proj_gemm<<<392, 256, 0, stream>>>(word, rel, Wn_w, Wn_b, Wr_w, Wr_b,
                                       lin_w, score_w, ws);
    attn_kernel<<<512, 256, 0, stream>>>(mask, ws);
    head_kernel<<<16, 512, 0, stream>>>(lin_w, lin_b, final_w, final_b,
                                        fc_w, fc_b, ws, out);
}